// Round 16
// baseline (190.998 us; speedup 1.0000x reference)
//
#include <hip/hip_runtime.h>
#include <hip/hip_fp16.h>

#define SEQ 2048
#define DIM 512

typedef __attribute__((ext_vector_type(8))) short short8;
typedef __attribute__((ext_vector_type(4))) float f32x4;
typedef _Float16 h8 __attribute__((ext_vector_type(8)));
typedef _Float16 h4 __attribute__((ext_vector_type(4)));

#define MFMA16(a, b, c) __builtin_amdgcn_mfma_f32_16x16x32_f16((a), (b), (c), 0, 0, 0)

#define GLOAD_LDS16(g, l)                                                              \
    __builtin_amdgcn_global_load_lds(                                                  \
        (const __attribute__((address_space(1))) unsigned int*)(g),                    \
        (__attribute__((address_space(3))) unsigned int*)(l), 16, 0, 0)

// ===== WIDE engine (R9-verified): 256x128, BK=64, 3 bufs, counted vmcnt ====
// 1D grid, XCD-aware decode: blocks sharing an A-tile land on one XCD.
// MODE 0: projQ  qh[16384,512] = xh @ Wq' (virtual K=1024 = [Wqh|Wql]) + bq
// MODE 1: projKV kh/vt = xh @ wkv (K=512; n0<512 -> K out, else V^T out)
template <int MODE>
__global__ __launch_bounds__(512, 1) void gemmw(
    const _Float16* __restrict__ A, const _Float16* __restrict__ B,
    const float* __restrict__ biasA, const float* __restrict__ biasB,
    _Float16* __restrict__ o0, _Float16* __restrict__ ovt) {
    extern __shared__ char sm[];     // 3 * 49152
    constexpr int T  = (MODE == 0) ? 16 : 8;
    constexpr int PA = 512;
    constexpr int PB = (MODE == 0) ? 1024 : 512;

    int tid = threadIdx.x, wid = tid >> 6, lane = tid & 63, r = lane & 15, g = lane >> 4;
    int wm = wid >> 1, wn = wid & 1;
    // XCD decode: same-A blocks at consecutive slots on one XCD
    int L = blockIdx.x, xcd = L & 7, s = L >> 3;
    int m0, n0;
    if (MODE == 0) { m0 = (xcd * 8 + (s >> 2)) * 256; n0 = (s & 3) * 128; }
    else           { m0 = (xcd * 8 + (s >> 3)) * 256; n0 = (s & 7) * 128; }

    const _Float16* Ab = A + (size_t)m0 * 512;
    const _Float16* Bb = B + (size_t)n0 * PB;

    const char* gA[4];
    const char* gB[2];
    int ldsA[4], ldsB[2];
#pragma unroll
    for (int j = 0; j < 4; ++j) {
        int ci = j * 512 + tid;
        int row = ci >> 3, cl = ci & 7;
        int col16 = cl ^ (row & 7);
        gA[j] = (const char*)Ab + (size_t)row * (PA * 2) + col16 * 16;
        ldsA[j] = ci * 16;
    }
#pragma unroll
    for (int j = 0; j < 2; ++j) {
        int ci = j * 512 + tid;
        int row = ci >> 3, cl = ci & 7;
        int col16 = cl ^ (row & 7);
        gB[j] = (const char*)Bb + (size_t)row * (PB * 2) + col16 * 16;
        ldsB[j] = ci * 16;
    }
    int offA[4][2], offB[4][2];
#pragma unroll
    for (int m = 0; m < 4; ++m) {
        int rowA = wm * 64 + m * 16 + r;
        int rowB = wn * 64 + m * 16 + r;
#pragma unroll
        for (int ks = 0; ks < 2; ++ks) {
            offA[m][ks] = rowA * 128 + (((ks * 4 + g) ^ (rowA & 7)) * 16);
            offB[m][ks] = rowB * 128 + (((ks * 4 + g) ^ (rowB & 7)) * 16);
        }
    }

    f32x4 acc[4][4];
#pragma unroll
    for (int m = 0; m < 4; ++m)
#pragma unroll
        for (int n = 0; n < 4; ++n) acc[m][n] = (f32x4)(0.0f);

    auto STG = [&](int t, int b) {
        int ka = (MODE == 0) ? ((t & 7) * 128) : (t * 128);
        int kb = t * 128;
        char* dA = sm + b * 49152;
        char* dB = sm + b * 49152 + 32768;
#pragma unroll
        for (int j = 0; j < 4; ++j) GLOAD_LDS16(gA[j] + ka, dA + ldsA[j]);
#pragma unroll
        for (int j = 0; j < 2; ++j) GLOAD_LDS16(gB[j] + kb, dB + ldsB[j]);
    };

    STG(0, 0);
    STG(1, 1);
    asm volatile("s_waitcnt vmcnt(6)" ::: "memory");
    __builtin_amdgcn_s_barrier();

#pragma unroll
    for (int t = 0; t < T; ++t) {
        const int buf = t % 3;
        if (t + 2 < T) STG(t + 2, (t + 2) % 3);
        const char* bA = sm + buf * 49152;
        const char* bB = sm + buf * 49152 + 32768;
        h8 af[4][2], bf[4][2];
#pragma unroll
        for (int m = 0; m < 4; ++m)
#pragma unroll
            for (int ks = 0; ks < 2; ++ks) {
                af[m][ks] = *(const h8*)(bA + offA[m][ks]);
                bf[m][ks] = *(const h8*)(bB + offB[m][ks]);
            }
        __builtin_amdgcn_s_setprio(1);
#pragma unroll
        for (int ks = 0; ks < 2; ++ks)
#pragma unroll
            for (int m = 0; m < 4; ++m)
#pragma unroll
                for (int n = 0; n < 4; ++n)
                    acc[m][n] = MFMA16(af[m][ks], bf[n][ks], acc[m][n]);
        __builtin_amdgcn_s_setprio(0);
        if (t + 2 < T) asm volatile("s_waitcnt vmcnt(6)" ::: "memory");
        else if (t + 1 < T) asm volatile("s_waitcnt vmcnt(0)" ::: "memory");
        if (t + 1 < T) __builtin_amdgcn_s_barrier();
    }

    if (MODE == 0) {
#pragma unroll
        for (int n = 0; n < 4; ++n) {
            int col = n0 + wn * 64 + n * 16 + r;
            float bi = biasA[col];
#pragma unroll
            for (int m = 0; m < 4; ++m) {
                int grow0 = m0 + wm * 64 + m * 16 + 4 * g;
                for (int reg = 0; reg < 4; ++reg)
                    o0[(size_t)(grow0 + reg) * 512 + col] =
                        (_Float16)(acc[m][n][reg] + bi);
            }
        }
    } else {
        int p = n0 >> 9, ncl = n0 & 511;
        if (p == 0) {
#pragma unroll
            for (int n = 0; n < 4; ++n) {
                int col = ncl + wn * 64 + n * 16 + r;
                float bi = biasA[col];
#pragma unroll
                for (int m = 0; m < 4; ++m) {
                    int grow0 = m0 + wm * 64 + m * 16 + 4 * g;
                    for (int reg = 0; reg < 4; ++reg)
                        o0[(size_t)(grow0 + reg) * 512 + col] =
                            (_Float16)(acc[m][n][reg] + bi);
                }
            }
        } else {
            // V^T via LDS transpose -> coalesced 128B-per-thread writes
            __syncthreads();
            _Float16* tt = (_Float16*)sm;    // [128 d][256 s], pitch 264 = 66KB
#pragma unroll
            for (int n = 0; n < 4; ++n) {
                int dloc = wn * 64 + n * 16 + r;
                float bi = biasB[ncl + dloc];
#pragma unroll
                for (int m = 0; m < 4; ++m) {
                    int sloc = wm * 64 + m * 16 + 4 * g;
                    h4 pv;
                    pv[0] = (_Float16)(acc[m][n][0] + bi);
                    pv[1] = (_Float16)(acc[m][n][1] + bi);
                    pv[2] = (_Float16)(acc[m][n][2] + bi);
                    pv[3] = (_Float16)(acc[m][n][3] + bi);
                    *(h4*)(&tt[dloc * 264 + sloc]) = pv;
                }
            }
            __syncthreads();
            int b = m0 >> 11, s0b = m0 & 2047;
            int drow = tid >> 2, part = tid & 3;
            const char* src = (const char*)(tt + drow * 264 + part * 64);
            char* dst = (char*)(ovt + (size_t)b * (512 * 2048) +
                                (size_t)(ncl + drow) * 2048 + s0b + part * 64);
#pragma unroll
            for (int j = 0; j < 8; ++j)
                *(short8*)(dst + j * 16) = *(const short8*)(src + j * 16);
        }
    }
}

// ===== NARROW engine (R8/R12-verified): 128x128, BK=64, dbuf ===============
// 1D grid, XCD decode: blocks sharing the A-panel sit on one XCD.
// MODE 1: qk  S[b][2048,2048] fp32 = Q @ K^T (K=512)
// MODE 2: pv  out[b][2048,512] = P @ V^T (K=2048; P f16 in S rows, pitch 4096)
template <int MODE>
__global__ __launch_bounds__(256) void gemmn(
    const _Float16* __restrict__ A, const _Float16* __restrict__ B,
    float* __restrict__ of, int bat0) {
    __shared__ char sm[2 * 32768];
    constexpr int T  = (MODE == 1) ? 8 : 32;
    constexpr int PA = (MODE == 1) ? 512 : 4096;
    constexpr int PB = (MODE == 1) ? 512 : 2048;

    int tid = threadIdx.x, wid = tid >> 6, lane = tid & 63, r = lane & 15, g = lane >> 4;
    int mw = wid >> 1, nw = wid & 1;
    int m0, n0, bz;
    {
        int L = blockIdx.x, xcd = L & 7, s = L >> 3;
        if (MODE == 1) {
            bz = s >> 5;
            int rem = s & 31;
            m0 = (xcd * 2 + (rem >> 4)) * 128;   // 16 m-tiles = 8 XCD x 2
            n0 = (rem & 15) * 128;               // 16 n-tiles
        } else {
            bz = s >> 3;
            int rem = s & 7;
            m0 = (xcd * 2 + (rem >> 2)) * 128;   // 16 m-tiles = 8 XCD x 2
            n0 = (rem & 3) * 128;                // 4 n-tiles
        }
    }

    const _Float16 *Ab, *Bb;
    if (MODE == 1) {
        int b = bat0 + bz;
        Ab = A + ((size_t)(b * SEQ) + m0) * 512;
        Bb = B + ((size_t)(b * SEQ) + n0) * 512;
    } else {
        int b = bat0 + bz;
        Ab = A + (size_t)bz * (SEQ * 4096) + (size_t)m0 * 4096;
        Bb = B + (size_t)b * (512 * SEQ) + (size_t)n0 * 2048;
    }

    const char* gA[4];
    const char* gB[4];
    int ldsw[4];
#pragma unroll
    for (int j = 0; j < 4; ++j) {
        int ci = (j * 4 + wid) * 64 + lane;
        int row = ci >> 3, cl = ci & 7;
        int col16 = cl ^ (row & 7);
        gA[j] = (const char*)Ab + (size_t)row * (PA * 2) + col16 * 16;
        gB[j] = (const char*)Bb + (size_t)row * (PB * 2) + col16 * 16;
        ldsw[j] = (j * 4 + wid) * 1024;
    }
    int offA[4][2], offB[4][2];
#pragma unroll
    for (int m = 0; m < 4; ++m) {
        int rowA = mw * 64 + m * 16 + r;
        int rowB = nw * 64 + m * 16 + r;
#pragma unroll
        for (int ks = 0; ks < 2; ++ks) {
            offA[m][ks] = rowA * 128 + (((ks * 4 + g) ^ (rowA & 7)) * 16);
            offB[m][ks] = rowB * 128 + (((ks * 4 + g) ^ (rowB & 7)) * 16);
        }
    }

    f32x4 acc[4][4];
#pragma unroll
    for (int m = 0; m < 4; ++m)
#pragma unroll
        for (int n = 0; n < 4; ++n) acc[m][n] = (f32x4)(0.0f);

    auto STG = [&](int t, int b) {
        int ka = t * 128, kb = t * 128;
        char* dA = sm + b * 32768;
        char* dB = sm + b * 32768 + 16384;
#pragma unroll
        for (int j = 0; j < 4; ++j) {
            GLOAD_LDS16(gA[j] + ka, dA + ldsw[j]);
            GLOAD_LDS16(gB[j] + kb, dB + ldsw[j]);
        }
    };

    STG(0, 0);
    asm volatile("s_waitcnt vmcnt(0)" ::: "memory");
    __builtin_amdgcn_s_barrier();

#pragma unroll
    for (int t = 0; t < T; ++t) {
        const int buf = t & 1;
        if (t + 1 < T) STG(t + 1, buf ^ 1);
        const char* bA = sm + buf * 32768;
        const char* bB = sm + buf * 32768 + 16384;
        h8 af[4][2], bf[4][2];
#pragma unroll
        for (int m = 0; m < 4; ++m)
#pragma unroll
            for (int ks = 0; ks < 2; ++ks) {
                af[m][ks] = *(const h8*)(bA + offA[m][ks]);
                bf[m][ks] = *(const h8*)(bB + offB[m][ks]);
            }
#pragma unroll
        for (int ks = 0; ks < 2; ++ks)
#pragma unroll
            for (int m = 0; m < 4; ++m)
#pragma unroll
                for (int n = 0; n < 4; ++n)
                    acc[m][n] = MFMA16(af[m][ks], bf[n][ks], acc[m][n]);
        if (t + 1 < T) {
            asm volatile("s_waitcnt vmcnt(0)" ::: "memory");
            __builtin_amdgcn_s_barrier();
        }
    }

    if (MODE == 1) {
        float* sb = of + (size_t)bz * (SEQ * (size_t)SEQ);
#pragma unroll
        for (int n = 0; n < 4; ++n) {
            int col = n0 + nw * 64 + n * 16 + r;
#pragma unroll
            for (int m = 0; m < 4; ++m) {
                int grow0 = m0 + mw * 64 + m * 16 + 4 * g;
                for (int reg = 0; reg < 4; ++reg)
                    sb[(size_t)(grow0 + reg) * SEQ + col] = acc[m][n][reg];
            }
        }
    } else {
        int b = bat0 + bz;
#pragma unroll
        for (int n = 0; n < 4; ++n) {
            int col = n0 + nw * 64 + n * 16 + r;
#pragma unroll
            for (int m = 0; m < 4; ++m) {
                int grow0 = m0 + mw * 64 + m * 16 + 4 * g;
                for (int reg = 0; reg < 4; ++reg)
                    of[(size_t)(b * SEQ + grow0 + reg) * 512 + col] = acc[m][n][reg];
            }
        }
    }
}

// ---------------- K3: row softmax, in-place P(f16) over S(f32) --------------
__global__ __launch_bounds__(256) void k3_softmax(float* __restrict__ sbuf) {
    size_t row = blockIdx.x;
    float* srow = sbuf + row * SEQ;
    int tid = threadIdx.x, lane = tid & 63, wid = tid >> 6;
    float4 v0 = *(const float4*)(srow + tid * 8);
    float4 v1 = *(const float4*)(srow + tid * 8 + 4);
    float m = fmaxf(fmaxf(fmaxf(v0.x, v0.y), fmaxf(v0.z, v0.w)),
                    fmaxf(fmaxf(v1.x, v1.y), fmaxf(v1.z, v1.w)));
    for (int d = 1; d < 64; d <<= 1) m = fmaxf(m, __shfl_xor(m, d));
    __shared__ float red1[4], red2[4];
    if (lane == 0) red1[wid] = m;
    __syncthreads();
    m = fmaxf(fmaxf(red1[0], red1[1]), fmaxf(red1[2], red1[3]));
    float e[8];
    e[0] = __expf(v0.x - m); e[1] = __expf(v0.y - m);
    e[2] = __expf(v0.z - m); e[3] = __expf(v0.w - m);
    e[4] = __expf(v1.x - m); e[5] = __expf(v1.y - m);
    e[6] = __expf(v1.z - m); e[7] = __expf(v1.w - m);
    float s = ((e[0] + e[1]) + (e[2] + e[3])) + ((e[4] + e[5]) + (e[6] + e[7]));
    for (int d = 1; d < 64; d <<= 1) s += __shfl_xor(s, d);
    if (lane == 0) red2[wid] = s;
    __syncthreads();
    s = (red2[0] + red2[1]) + (red2[2] + red2[3]);
    float inv = 1.0f / s;
    h8 ph;
    for (int j = 0; j < 8; ++j) ph[j] = (_Float16)(e[j] * inv);
    *(h8*)((char*)srow + (size_t)tid * 16) = ph;   // P row: first 4KB of S row
}

// ---------------- K0a: Wq -> hi|lo stacked (K=1024); Wk,Wv -> hi only -------
__global__ __launch_bounds__(256) void k0a_splitw(
    const float* __restrict__ Wq, const float* __restrict__ Wk, const float* __restrict__ Wv,
    _Float16* __restrict__ wq, _Float16* __restrict__ wkv) {
    int idx = blockIdx.x * 256 + threadIdx.x;   // [0, 3*512*512)
    int p = idx >> 18;
    int rem = idx & 262143;
    int k = rem >> 9, n = rem & 511;
    if (p == 0) {
        float w = Wq[rem];
        _Float16 h = (_Float16)w;
        wq[(size_t)n * 1024 + k] = h;
        wq[(size_t)n * 1024 + 512 + k] = (_Float16)(w - (float)h);
    } else if (p == 1) {
        wkv[(size_t)n * 512 + k] = (_Float16)Wk[rem];
    } else {
        wkv[(size_t)(512 + n) * 512 + k] = (_Float16)Wv[rem];
    }
}

// ---------------- K0b: x -> f16 ---------------------------------------------
__global__ __launch_bounds__(256) void k0b_splitx(
    const float* __restrict__ x, _Float16* __restrict__ xh) {
    size_t i = (size_t)(blockIdx.x * 256 + threadIdx.x) * 4;
    float4 v = *(const float4*)(x + i);
    h4 h;
    h[0] = (_Float16)v.x; h[1] = (_Float16)v.y;
    h[2] = (_Float16)v.z; h[3] = (_Float16)v.w;
    *(h4*)(xh + i) = h;
}

// ---------------------------------------------------------------------------
extern "C" void kernel_launch(void* const* d_in, const int* in_sizes, int n_in,
                              void* d_out, int out_size, void* d_ws, size_t ws_size,
                              hipStream_t stream) {
    const float* x  = (const float*)d_in[0];
    const float* Wq = (const float*)d_in[1];
    const float* bq = (const float*)d_in[2];
    const float* Wk = (const float*)d_in[3];
    const float* bk = (const float*)d_in[4];
    const float* Wv = (const float*)d_in[5];
    const float* bv = (const float*)d_in[6];
    float* out = (float*)d_out;

    char* ws = (char*)d_ws;
    const size_t QSZ = 16777216;   // 16384*512*2B (= one batch of S fp32)
    _Float16* wq  = (_Float16*)(ws);                    // 1MB
    _Float16* wkv = (_Float16*)(ws + 1048576);          // 1MB
    _Float16* xh = (_Float16*)(ws + 3145728);
    _Float16* qh = (_Float16*)(ws + 3145728 + 1 * QSZ);
    _Float16* kh = (_Float16*)(ws + 3145728 + 2 * QSZ);
    _Float16* vt = (_Float16*)(ws + 3145728 + 3 * QSZ);
    const size_t sbase = 3145728 + 4 * QSZ;             // 70,254,592

    const int LDSW = 3 * 49152;   // 144 KB
    hipFuncSetAttribute((const void*)gemmw<0>,
                        hipFuncAttributeMaxDynamicSharedMemorySize, LDSW);
    hipFuncSetAttribute((const void*)gemmw<1>,
                        hipFuncAttributeMaxDynamicSharedMemorySize, LDSW);

    k0a_splitw<<<3072, 256, 0, stream>>>(Wq, Wk, Wv, wq, wkv);
    k0b_splitx<<<8192, 256, 0, stream>>>(x, xh);
    gemmw<0><<<256, 512, LDSW, stream>>>(xh, wq, bq, nullptr, qh, nullptr);
    gemmw<1><<<512, 512, LDSW, stream>>>(xh, wkv, bk, bv, kh, vt);

    // chunked attention; chunk capped at 4 so S (64MB) stays L3-resident and
    // pv grid (chunk*64 = 256 blocks) is exactly one CU generation.
    size_t avail = (ws_size > sbase) ? (ws_size - sbase) : 0;
    int chunk = (int)(avail / QSZ);
    if (chunk < 1) chunk = 1;
    if (chunk > 4) chunk = 4;
    float* sc = (float*)(ws + sbase);
    for (int b0 = 0; b0 < 8; b0 += chunk) {
        int nb = (8 - b0 < chunk) ? (8 - b0) : chunk;
        gemmn<1><<<nb * 256, 256, 0, stream>>>(qh, kh, sc, b0);
        k3_softmax<<<dim3(nb * SEQ), 256, 0, stream>>>(sc);
        gemmn<2><<<nb * 64, 256, 0, stream>>>((const _Float16*)sc, vt, out, b0);
    }
}

// Round 17
// 173.639 us; speedup vs baseline: 1.1000x; 1.1000x over previous
//
#include <hip/hip_runtime.h>
#include <hip/hip_fp16.h>

#define SEQ 2048
#define DIM 512

typedef __attribute__((ext_vector_type(8))) short short8;
typedef __attribute__((ext_vector_type(4))) float f32x4;
typedef _Float16 h8 __attribute__((ext_vector_type(8)));
typedef _Float16 h4 __attribute__((ext_vector_type(4)));

#define MFMA16(a, b, c) __builtin_amdgcn_mfma_f32_16x16x32_f16((a), (b), (c), 0, 0, 0)

#define GLOAD_LDS16(g, l)                                                              \
    __builtin_amdgcn_global_load_lds(                                                  \
        (const __attribute__((address_space(1))) unsigned int*)(g),                    \
        (__attribute__((address_space(3))) unsigned int*)(l), 16, 0, 0)

// ===== WIDE engine (R9-verified): 256x128, BK=64, 3 bufs, counted vmcnt ====
// 1D grid, XCD-aware decode: blocks sharing an A-tile land on one XCD.
// MODE 0: projQ  qh[16384,512] = xh @ Wq' (virtual K=1024 = [Wqh|Wql]) + bq
// MODE 1: projKV kh/vt = xh @ wkv (K=512; n0<512 -> K out, else V^T out)
template <int MODE>
__global__ __launch_bounds__(512, 1) void gemmw(
    const _Float16* __restrict__ A, const _Float16* __restrict__ B,
    const float* __restrict__ biasA, const float* __restrict__ biasB,
    _Float16* __restrict__ o0, _Float16* __restrict__ ovt) {
    extern __shared__ char sm[];     // 3 * 49152
    constexpr int T  = (MODE == 0) ? 16 : 8;
    constexpr int PA = 512;
    constexpr int PB = (MODE == 0) ? 1024 : 512;

    int tid = threadIdx.x, wid = tid >> 6, lane = tid & 63, r = lane & 15, g = lane >> 4;
    int wm = wid >> 1, wn = wid & 1;
    // XCD decode: same-A blocks at consecutive slots on one XCD
    int L = blockIdx.x, xcd = L & 7, s = L >> 3;
    int m0, n0;
    if (MODE == 0) { m0 = (xcd * 8 + (s >> 2)) * 256; n0 = (s & 3) * 128; }
    else           { m0 = (xcd * 8 + (s >> 3)) * 256; n0 = (s & 7) * 128; }

    const _Float16* Ab = A + (size_t)m0 * 512;
    const _Float16* Bb = B + (size_t)n0 * PB;

    const char* gA[4];
    const char* gB[2];
    int ldsA[4], ldsB[2];
#pragma unroll
    for (int j = 0; j < 4; ++j) {
        int ci = j * 512 + tid;
        int row = ci >> 3, cl = ci & 7;
        int col16 = cl ^ (row & 7);
        gA[j] = (const char*)Ab + (size_t)row * (PA * 2) + col16 * 16;
        ldsA[j] = ci * 16;
    }
#pragma unroll
    for (int j = 0; j < 2; ++j) {
        int ci = j * 512 + tid;
        int row = ci >> 3, cl = ci & 7;
        int col16 = cl ^ (row & 7);
        gB[j] = (const char*)Bb + (size_t)row * (PB * 2) + col16 * 16;
        ldsB[j] = ci * 16;
    }
    int offA[4][2], offB[4][2];
#pragma unroll
    for (int m = 0; m < 4; ++m) {
        int rowA = wm * 64 + m * 16 + r;
        int rowB = wn * 64 + m * 16 + r;
#pragma unroll
        for (int ks = 0; ks < 2; ++ks) {
            offA[m][ks] = rowA * 128 + (((ks * 4 + g) ^ (rowA & 7)) * 16);
            offB[m][ks] = rowB * 128 + (((ks * 4 + g) ^ (rowB & 7)) * 16);
        }
    }

    f32x4 acc[4][4];
#pragma unroll
    for (int m = 0; m < 4; ++m)
#pragma unroll
        for (int n = 0; n < 4; ++n) acc[m][n] = (f32x4)(0.0f);

    auto STG = [&](int t, int b) {
        int ka = (MODE == 0) ? ((t & 7) * 128) : (t * 128);
        int kb = t * 128;
        char* dA = sm + b * 49152;
        char* dB = sm + b * 49152 + 32768;
#pragma unroll
        for (int j = 0; j < 4; ++j) GLOAD_LDS16(gA[j] + ka, dA + ldsA[j]);
#pragma unroll
        for (int j = 0; j < 2; ++j) GLOAD_LDS16(gB[j] + kb, dB + ldsB[j]);
    };

    STG(0, 0);
    STG(1, 1);
    asm volatile("s_waitcnt vmcnt(6)" ::: "memory");
    __builtin_amdgcn_s_barrier();

#pragma unroll
    for (int t = 0; t < T; ++t) {
        const int buf = t % 3;
        if (t + 2 < T) STG(t + 2, (t + 2) % 3);
        const char* bA = sm + buf * 49152;
        const char* bB = sm + buf * 49152 + 32768;
        h8 af[4][2], bf[4][2];
#pragma unroll
        for (int m = 0; m < 4; ++m)
#pragma unroll
            for (int ks = 0; ks < 2; ++ks) {
                af[m][ks] = *(const h8*)(bA + offA[m][ks]);
                bf[m][ks] = *(const h8*)(bB + offB[m][ks]);
            }
        __builtin_amdgcn_s_setprio(1);
#pragma unroll
        for (int ks = 0; ks < 2; ++ks)
#pragma unroll
            for (int m = 0; m < 4; ++m)
#pragma unroll
                for (int n = 0; n < 4; ++n)
                    acc[m][n] = MFMA16(af[m][ks], bf[n][ks], acc[m][n]);
        __builtin_amdgcn_s_setprio(0);
        if (t + 2 < T) asm volatile("s_waitcnt vmcnt(6)" ::: "memory");
        else if (t + 1 < T) asm volatile("s_waitcnt vmcnt(0)" ::: "memory");
        if (t + 1 < T) __builtin_amdgcn_s_barrier();
    }

    if (MODE == 0) {
#pragma unroll
        for (int n = 0; n < 4; ++n) {
            int col = n0 + wn * 64 + n * 16 + r;
            float bi = biasA[col];
#pragma unroll
            for (int m = 0; m < 4; ++m) {
                int grow0 = m0 + wm * 64 + m * 16 + 4 * g;
                for (int reg = 0; reg < 4; ++reg)
                    o0[(size_t)(grow0 + reg) * 512 + col] =
                        (_Float16)(acc[m][n][reg] + bi);
            }
        }
    } else {
        int p = n0 >> 9, ncl = n0 & 511;
        if (p == 0) {
#pragma unroll
            for (int n = 0; n < 4; ++n) {
                int col = ncl + wn * 64 + n * 16 + r;
                float bi = biasA[col];
#pragma unroll
                for (int m = 0; m < 4; ++m) {
                    int grow0 = m0 + wm * 64 + m * 16 + 4 * g;
                    for (int reg = 0; reg < 4; ++reg)
                        o0[(size_t)(grow0 + reg) * 512 + col] =
                            (_Float16)(acc[m][n][reg] + bi);
                }
            }
        } else {
            // V^T via LDS transpose -> coalesced 128B-per-thread writes
            __syncthreads();
            _Float16* tt = (_Float16*)sm;    // [128 d][256 s], pitch 264 = 66KB
#pragma unroll
            for (int n = 0; n < 4; ++n) {
                int dloc = wn * 64 + n * 16 + r;
                float bi = biasB[ncl + dloc];
#pragma unroll
                for (int m = 0; m < 4; ++m) {
                    int sloc = wm * 64 + m * 16 + 4 * g;
                    h4 pv;
                    pv[0] = (_Float16)(acc[m][n][0] + bi);
                    pv[1] = (_Float16)(acc[m][n][1] + bi);
                    pv[2] = (_Float16)(acc[m][n][2] + bi);
                    pv[3] = (_Float16)(acc[m][n][3] + bi);
                    *(h4*)(&tt[dloc * 264 + sloc]) = pv;
                }
            }
            __syncthreads();
            int b = m0 >> 11, s0b = m0 & 2047;
            int drow = tid >> 2, part = tid & 3;
            const char* src = (const char*)(tt + drow * 264 + part * 64);
            char* dst = (char*)(ovt + (size_t)b * (512 * 2048) +
                                (size_t)(ncl + drow) * 2048 + s0b + part * 64);
#pragma unroll
            for (int j = 0; j < 8; ++j)
                *(short8*)(dst + j * 16) = *(const short8*)(src + j * 16);
        }
    }
}

// ===== NARROW engine (R8/R12-verified): 128x128, BK=64, dbuf ===============
// 1D grid, XCD decode: blocks sharing the A-panel sit on one XCD.
// MODE 1: qk  S[b][2048,2048] fp32 = Q @ K^T (K=512)
// MODE 2: pv  out[b][2048,512] = P @ V^T (K=2048; P f16 in S rows, pitch 4096)
template <int MODE>
__global__ __launch_bounds__(256) void gemmn(
    const _Float16* __restrict__ A, const _Float16* __restrict__ B,
    float* __restrict__ of, int bat0) {
    __shared__ char sm[2 * 32768];
    constexpr int T  = (MODE == 1) ? 8 : 32;
    constexpr int PA = (MODE == 1) ? 512 : 4096;
    constexpr int PB = (MODE == 1) ? 512 : 2048;

    int tid = threadIdx.x, wid = tid >> 6, lane = tid & 63, r = lane & 15, g = lane >> 4;
    int mw = wid >> 1, nw = wid & 1;
    int m0, n0, bz;
    {
        int L = blockIdx.x, xcd = L & 7, s = L >> 3;
        if (MODE == 1) {
            bz = s >> 5;
            int rem = s & 31;
            m0 = (xcd * 2 + (rem >> 4)) * 128;   // 16 m-tiles = 8 XCD x 2
            n0 = (rem & 15) * 128;               // 16 n-tiles
        } else {
            bz = s >> 3;
            int rem = s & 7;
            m0 = (xcd * 2 + (rem >> 2)) * 128;   // 16 m-tiles = 8 XCD x 2
            n0 = (rem & 3) * 128;                // 4 n-tiles
        }
    }

    const _Float16 *Ab, *Bb;
    if (MODE == 1) {
        int b = bat0 + bz;
        Ab = A + ((size_t)(b * SEQ) + m0) * 512;
        Bb = B + ((size_t)(b * SEQ) + n0) * 512;
    } else {
        int b = bat0 + bz;
        Ab = A + (size_t)bz * (SEQ * 4096) + (size_t)m0 * 4096;
        Bb = B + (size_t)b * (512 * SEQ) + (size_t)n0 * 2048;
    }

    const char* gA[4];
    const char* gB[4];
    int ldsw[4];
#pragma unroll
    for (int j = 0; j < 4; ++j) {
        int ci = (j * 4 + wid) * 64 + lane;
        int row = ci >> 3, cl = ci & 7;
        int col16 = cl ^ (row & 7);
        gA[j] = (const char*)Ab + (size_t)row * (PA * 2) + col16 * 16;
        gB[j] = (const char*)Bb + (size_t)row * (PB * 2) + col16 * 16;
        ldsw[j] = (j * 4 + wid) * 1024;
    }
    int offA[4][2], offB[4][2];
#pragma unroll
    for (int m = 0; m < 4; ++m) {
        int rowA = mw * 64 + m * 16 + r;
        int rowB = nw * 64 + m * 16 + r;
#pragma unroll
        for (int ks = 0; ks < 2; ++ks) {
            offA[m][ks] = rowA * 128 + (((ks * 4 + g) ^ (rowA & 7)) * 16);
            offB[m][ks] = rowB * 128 + (((ks * 4 + g) ^ (rowB & 7)) * 16);
        }
    }

    f32x4 acc[4][4];
#pragma unroll
    for (int m = 0; m < 4; ++m)
#pragma unroll
        for (int n = 0; n < 4; ++n) acc[m][n] = (f32x4)(0.0f);

    auto STG = [&](int t, int b) {
        int ka = t * 128, kb = t * 128;
        char* dA = sm + b * 32768;
        char* dB = sm + b * 32768 + 16384;
#pragma unroll
        for (int j = 0; j < 4; ++j) {
            GLOAD_LDS16(gA[j] + ka, dA + ldsw[j]);
            GLOAD_LDS16(gB[j] + kb, dB + ldsw[j]);
        }
    };

    STG(0, 0);
    asm volatile("s_waitcnt vmcnt(0)" ::: "memory");
    __builtin_amdgcn_s_barrier();

#pragma unroll
    for (int t = 0; t < T; ++t) {
        const int buf = t & 1;
        if (t + 1 < T) STG(t + 1, buf ^ 1);
        const char* bA = sm + buf * 32768;
        const char* bB = sm + buf * 32768 + 16384;
        h8 af[4][2], bf[4][2];
#pragma unroll
        for (int m = 0; m < 4; ++m)
#pragma unroll
            for (int ks = 0; ks < 2; ++ks) {
                af[m][ks] = *(const h8*)(bA + offA[m][ks]);
                bf[m][ks] = *(const h8*)(bB + offB[m][ks]);
            }
#pragma unroll
        for (int ks = 0; ks < 2; ++ks)
#pragma unroll
            for (int m = 0; m < 4; ++m)
#pragma unroll
                for (int n = 0; n < 4; ++n)
                    acc[m][n] = MFMA16(af[m][ks], bf[n][ks], acc[m][n]);
        if (t + 1 < T) {
            asm volatile("s_waitcnt vmcnt(0)" ::: "memory");
            __builtin_amdgcn_s_barrier();
        }
    }

    if (MODE == 1) {
        float* sb = of + (size_t)bz * (SEQ * (size_t)SEQ);
#pragma unroll
        for (int n = 0; n < 4; ++n) {
            int col = n0 + nw * 64 + n * 16 + r;
#pragma unroll
            for (int m = 0; m < 4; ++m) {
                int grow0 = m0 + mw * 64 + m * 16 + 4 * g;
                for (int reg = 0; reg < 4; ++reg)
                    sb[(size_t)(grow0 + reg) * SEQ + col] = acc[m][n][reg];
            }
        }
    } else {
        int b = bat0 + bz;
#pragma unroll
        for (int n = 0; n < 4; ++n) {
            int col = n0 + nw * 64 + n * 16 + r;
#pragma unroll
            for (int m = 0; m < 4; ++m) {
                int grow0 = m0 + mw * 64 + m * 16 + 4 * g;
                for (int reg = 0; reg < 4; ++reg)
                    of[(size_t)(b * SEQ + grow0 + reg) * 512 + col] = acc[m][n][reg];
            }
        }
    }
}

// ---------------- K3: row softmax, in-place P(f16) over S(f32) --------------
__global__ __launch_bounds__(256) void k3_softmax(float* __restrict__ sbuf) {
    size_t row = blockIdx.x;
    float* srow = sbuf + row * SEQ;
    int tid = threadIdx.x, lane = tid & 63, wid = tid >> 6;
    float4 v0 = *(const float4*)(srow + tid * 8);
    float4 v1 = *(const float4*)(srow + tid * 8 + 4);
    float m = fmaxf(fmaxf(fmaxf(v0.x, v0.y), fmaxf(v0.z, v0.w)),
                    fmaxf(fmaxf(v1.x, v1.y), fmaxf(v1.z, v1.w)));
    for (int d = 1; d < 64; d <<= 1) m = fmaxf(m, __shfl_xor(m, d));
    __shared__ float red1[4], red2[4];
    if (lane == 0) red1[wid] = m;
    __syncthreads();
    m = fmaxf(fmaxf(red1[0], red1[1]), fmaxf(red1[2], red1[3]));
    float e[8];
    e[0] = __expf(v0.x - m); e[1] = __expf(v0.y - m);
    e[2] = __expf(v0.z - m); e[3] = __expf(v0.w - m);
    e[4] = __expf(v1.x - m); e[5] = __expf(v1.y - m);
    e[6] = __expf(v1.z - m); e[7] = __expf(v1.w - m);
    float s = ((e[0] + e[1]) + (e[2] + e[3])) + ((e[4] + e[5]) + (e[6] + e[7]));
    for (int d = 1; d < 64; d <<= 1) s += __shfl_xor(s, d);
    if (lane == 0) red2[wid] = s;
    __syncthreads();
    s = (red2[0] + red2[1]) + (red2[2] + red2[3]);
    float inv = 1.0f / s;
    h8 ph;
    for (int j = 0; j < 8; ++j) ph[j] = (_Float16)(e[j] * inv);
    *(h8*)((char*)srow + (size_t)tid * 16) = ph;   // P row: first 4KB of S row
}

// ---------------- K0a: Wq -> hi|lo stacked (K=1024); Wk,Wv -> hi only -------
__global__ __launch_bounds__(256) void k0a_splitw(
    const float* __restrict__ Wq, const float* __restrict__ Wk, const float* __restrict__ Wv,
    _Float16* __restrict__ wq, _Float16* __restrict__ wkv) {
    int idx = blockIdx.x * 256 + threadIdx.x;   // [0, 3*512*512)
    int p = idx >> 18;
    int rem = idx & 262143;
    int k = rem >> 9, n = rem & 511;
    if (p == 0) {
        float w = Wq[rem];
        _Float16 h = (_Float16)w;
        wq[(size_t)n * 1024 + k] = h;
        wq[(size_t)n * 1024 + 512 + k] = (_Float16)(w - (float)h);
    } else if (p == 1) {
        wkv[(size_t)n * 512 + k] = (_Float16)Wk[rem];
    } else {
        wkv[(size_t)(512 + n) * 512 + k] = (_Float16)Wv[rem];
    }
}

// ---------------- K0b: x -> f16 ---------------------------------------------
__global__ __launch_bounds__(256) void k0b_splitx(
    const float* __restrict__ x, _Float16* __restrict__ xh) {
    size_t i = (size_t)(blockIdx.x * 256 + threadIdx.x) * 4;
    float4 v = *(const float4*)(x + i);
    h4 h;
    h[0] = (_Float16)v.x; h[1] = (_Float16)v.y;
    h[2] = (_Float16)v.z; h[3] = (_Float16)v.w;
    *(h4*)(xh + i) = h;
}

// ---------------------------------------------------------------------------
extern "C" void kernel_launch(void* const* d_in, const int* in_sizes, int n_in,
                              void* d_out, int out_size, void* d_ws, size_t ws_size,
                              hipStream_t stream) {
    const float* x  = (const float*)d_in[0];
    const float* Wq = (const float*)d_in[1];
    const float* bq = (const float*)d_in[2];
    const float* Wk = (const float*)d_in[3];
    const float* bk = (const float*)d_in[4];
    const float* Wv = (const float*)d_in[5];
    const float* bv = (const float*)d_in[6];
    float* out = (float*)d_out;

    char* ws = (char*)d_ws;
    const size_t QSZ = 16777216;   // 16384*512*2B (= one batch of S fp32)
    _Float16* wq  = (_Float16*)(ws);                    // 1MB
    _Float16* wkv = (_Float16*)(ws + 1048576);          // 1MB
    _Float16* xh = (_Float16*)(ws + 3145728);
    _Float16* qh = (_Float16*)(ws + 3145728 + 1 * QSZ);
    _Float16* kh = (_Float16*)(ws + 3145728 + 2 * QSZ);
    _Float16* vt = (_Float16*)(ws + 3145728 + 3 * QSZ);
    const size_t sbase = 3145728 + 4 * QSZ;             // 70,254,592

    const int LDSW = 3 * 49152;   // 144 KB
    hipFuncSetAttribute((const void*)gemmw<0>,
                        hipFuncAttributeMaxDynamicSharedMemorySize, LDSW);
    hipFuncSetAttribute((const void*)gemmw<1>,
                        hipFuncAttributeMaxDynamicSharedMemorySize, LDSW);

    k0a_splitw<<<3072, 256, 0, stream>>>(Wq, Wk, Wv, wq, wkv);
    k0b_splitx<<<8192, 256, 0, stream>>>(x, xh);
    gemmw<0><<<256, 512, LDSW, stream>>>(xh, wq, bq, nullptr, qh, nullptr);
    gemmw<1><<<512, 512, LDSW, stream>>>(xh, wkv, bk, bv, kh, vt);

    // chunked attention; chunk=8 restores pv to 512 blocks (2 blocks/CU —
    // R16 showed 256 blocks = 1/CU halves MfmaUtil). XCD decode kept (R16:
    // FETCH_SIZE halved).
    size_t avail = (ws_size > sbase) ? (ws_size - sbase) : 0;
    int chunk = (int)(avail / QSZ);
    if (chunk < 1) chunk = 1;
    if (chunk > 8) chunk = 8;
    float* sc = (float*)(ws + sbase);
    for (int b0 = 0; b0 < 8; b0 += chunk) {
        int nb = (8 - b0 < chunk) ? (8 - b0) : chunk;
        gemmn<1><<<nb * 256, 256, 0, stream>>>(qh, kh, sc, b0);
        k3_softmax<<<dim3(nb * SEQ), 256, 0, stream>>>(sc);
        gemmn<2><<<nb * 64, 256, 0, stream>>>((const _Float16*)sc, vt, out, b0);
    }
}

// Round 18
// 173.058 us; speedup vs baseline: 1.1037x; 1.0034x over previous
//
#include <hip/hip_runtime.h>
#include <hip/hip_fp16.h>

#define SEQ 2048
#define DIM 512

typedef __attribute__((ext_vector_type(8))) short short8;
typedef __attribute__((ext_vector_type(4))) float f32x4;
typedef _Float16 h8 __attribute__((ext_vector_type(8)));
typedef _Float16 h4 __attribute__((ext_vector_type(4)));

#define MFMA16(a, b, c) __builtin_amdgcn_mfma_f32_16x16x32_f16((a), (b), (c), 0, 0, 0)

#define GLOAD_LDS16(g, l)                                                              \
    __builtin_amdgcn_global_load_lds(                                                  \
        (const __attribute__((address_space(1))) unsigned int*)(g),                    \
        (__attribute__((address_space(3))) unsigned int*)(l), 16, 0, 0)

// ===== WIDE engine (R9-verified): 256x128, BK=64, 3 bufs, counted vmcnt ====
// 512 threads, 144KB LDS, 1 block/CU (by design). 1D grid, XCD-aware decode.
// MODE 0: projQ  qh[16384,512] = xh @ Wq' (virtual K=1024 = [Wqh|Wql]) + bq
// MODE 1: projKV kh/vt = xh @ wkv (K=512; n0<512 -> K out, else V^T out)
// MODE 2: pv     out[b][2048,512] = P @ V^T (K=2048; P f16 rows pitch 4096)
template <int MODE>
__global__ __launch_bounds__(512, 1) void gemmw(
    const _Float16* __restrict__ A, const _Float16* __restrict__ B,
    const float* __restrict__ biasA, const float* __restrict__ biasB,
    _Float16* __restrict__ o0, _Float16* __restrict__ ovt,
    float* __restrict__ ofp, int bat0) {
    extern __shared__ char sm[];     // 3 * 49152
    constexpr int T  = (MODE == 0) ? 16 : (MODE == 1) ? 8 : 32;
    constexpr int PA = (MODE == 2) ? 4096 : 512;
    constexpr int PB = (MODE == 0) ? 1024 : (MODE == 1) ? 512 : 2048;

    int tid = threadIdx.x, wid = tid >> 6, lane = tid & 63, r = lane & 15, g = lane >> 4;
    int wm = wid >> 1, wn = wid & 1;
    // XCD decode: same-A blocks at consecutive slots on one XCD
    int L = blockIdx.x, xcd = L & 7, s = L >> 3;
    int m0, n0, bz = 0;
    if (MODE == 0)      { m0 = (xcd * 8 + (s >> 2)) * 256; n0 = (s & 3) * 128; }
    else if (MODE == 1) { m0 = (xcd * 8 + (s >> 3)) * 256; n0 = (s & 7) * 128; }
    else                { m0 = xcd * 256; bz = s >> 2; n0 = (s & 3) * 128; }

    const _Float16 *Ab, *Bb;
    if (MODE == 2) {
        int b = bat0 + bz;
        Ab = A + (size_t)bz * (SEQ * 4096) + (size_t)m0 * 4096;
        Bb = B + (size_t)b * (512 * SEQ) + (size_t)n0 * 2048;
    } else {
        Ab = A + (size_t)m0 * 512;
        Bb = B + (size_t)n0 * PB;
    }

    const char* gA[4];
    const char* gB[2];
    int ldsA[4], ldsB[2];
#pragma unroll
    for (int j = 0; j < 4; ++j) {
        int ci = j * 512 + tid;
        int row = ci >> 3, cl = ci & 7;
        int col16 = cl ^ (row & 7);
        gA[j] = (const char*)Ab + (size_t)row * (PA * 2) + col16 * 16;
        ldsA[j] = ci * 16;
    }
#pragma unroll
    for (int j = 0; j < 2; ++j) {
        int ci = j * 512 + tid;
        int row = ci >> 3, cl = ci & 7;
        int col16 = cl ^ (row & 7);
        gB[j] = (const char*)Bb + (size_t)row * (PB * 2) + col16 * 16;
        ldsB[j] = ci * 16;
    }
    int offA[4][2], offB[4][2];
#pragma unroll
    for (int m = 0; m < 4; ++m) {
        int rowA = wm * 64 + m * 16 + r;
        int rowB = wn * 64 + m * 16 + r;
#pragma unroll
        for (int ks = 0; ks < 2; ++ks) {
            offA[m][ks] = rowA * 128 + (((ks * 4 + g) ^ (rowA & 7)) * 16);
            offB[m][ks] = rowB * 128 + (((ks * 4 + g) ^ (rowB & 7)) * 16);
        }
    }

    f32x4 acc[4][4];
#pragma unroll
    for (int m = 0; m < 4; ++m)
#pragma unroll
        for (int n = 0; n < 4; ++n) acc[m][n] = (f32x4)(0.0f);

    auto STG = [&](int t, int b) {
        int ka = (MODE == 0) ? ((t & 7) * 128) : (t * 128);
        int kb = t * 128;
        char* dA = sm + b * 49152;
        char* dB = sm + b * 49152 + 32768;
#pragma unroll
        for (int j = 0; j < 4; ++j) GLOAD_LDS16(gA[j] + ka, dA + ldsA[j]);
#pragma unroll
        for (int j = 0; j < 2; ++j) GLOAD_LDS16(gB[j] + kb, dB + ldsB[j]);
    };

    STG(0, 0);
    STG(1, 1);
    asm volatile("s_waitcnt vmcnt(6)" ::: "memory");
    __builtin_amdgcn_s_barrier();

#pragma unroll
    for (int t = 0; t < T; ++t) {
        const int buf = t % 3;
        if (t + 2 < T) STG(t + 2, (t + 2) % 3);
        const char* bA = sm + buf * 49152;
        const char* bB = sm + buf * 49152 + 32768;
        h8 af[4][2], bf[4][2];
#pragma unroll
        for (int m = 0; m < 4; ++m)
#pragma unroll
            for (int ks = 0; ks < 2; ++ks) {
                af[m][ks] = *(const h8*)(bA + offA[m][ks]);
                bf[m][ks] = *(const h8*)(bB + offB[m][ks]);
            }
        __builtin_amdgcn_s_setprio(1);
#pragma unroll
        for (int ks = 0; ks < 2; ++ks)
#pragma unroll
            for (int m = 0; m < 4; ++m)
#pragma unroll
                for (int n = 0; n < 4; ++n)
                    acc[m][n] = MFMA16(af[m][ks], bf[n][ks], acc[m][n]);
        __builtin_amdgcn_s_setprio(0);
        if (t + 2 < T) asm volatile("s_waitcnt vmcnt(6)" ::: "memory");
        else if (t + 1 < T) asm volatile("s_waitcnt vmcnt(0)" ::: "memory");
        if (t + 1 < T) __builtin_amdgcn_s_barrier();
    }

    if (MODE == 0) {
#pragma unroll
        for (int n = 0; n < 4; ++n) {
            int col = n0 + wn * 64 + n * 16 + r;
            float bi = biasA[col];
#pragma unroll
            for (int m = 0; m < 4; ++m) {
                int grow0 = m0 + wm * 64 + m * 16 + 4 * g;
                for (int reg = 0; reg < 4; ++reg)
                    o0[(size_t)(grow0 + reg) * 512 + col] =
                        (_Float16)(acc[m][n][reg] + bi);
            }
        }
    } else if (MODE == 1) {
        int p = n0 >> 9, ncl = n0 & 511;
        if (p == 0) {
#pragma unroll
            for (int n = 0; n < 4; ++n) {
                int col = ncl + wn * 64 + n * 16 + r;
                float bi = biasA[col];
#pragma unroll
                for (int m = 0; m < 4; ++m) {
                    int grow0 = m0 + wm * 64 + m * 16 + 4 * g;
                    for (int reg = 0; reg < 4; ++reg)
                        o0[(size_t)(grow0 + reg) * 512 + col] =
                            (_Float16)(acc[m][n][reg] + bi);
                }
            }
        } else {
            // V^T via LDS transpose -> coalesced 128B-per-thread writes
            __syncthreads();
            _Float16* tt = (_Float16*)sm;    // [128 d][256 s], pitch 264 = 66KB
#pragma unroll
            for (int n = 0; n < 4; ++n) {
                int dloc = wn * 64 + n * 16 + r;
                float bi = biasB[ncl + dloc];
#pragma unroll
                for (int m = 0; m < 4; ++m) {
                    int sloc = wm * 64 + m * 16 + 4 * g;
                    h4 pv;
                    pv[0] = (_Float16)(acc[m][n][0] + bi);
                    pv[1] = (_Float16)(acc[m][n][1] + bi);
                    pv[2] = (_Float16)(acc[m][n][2] + bi);
                    pv[3] = (_Float16)(acc[m][n][3] + bi);
                    *(h4*)(&tt[dloc * 264 + sloc]) = pv;
                }
            }
            __syncthreads();
            int b = m0 >> 11, s0b = m0 & 2047;
            int drow = tid >> 2, part = tid & 3;
            const char* src = (const char*)(tt + drow * 264 + part * 64);
            char* dst = (char*)(ovt + (size_t)b * (512 * 2048) +
                                (size_t)(ncl + drow) * 2048 + s0b + part * 64);
#pragma unroll
            for (int j = 0; j < 8; ++j)
                *(short8*)(dst + j * 16) = *(const short8*)(src + j * 16);
        }
    } else {
        int b = bat0 + bz;
#pragma unroll
        for (int n = 0; n < 4; ++n) {
            int col = n0 + wn * 64 + n * 16 + r;
#pragma unroll
            for (int m = 0; m < 4; ++m) {
                int grow0 = m0 + wm * 64 + m * 16 + 4 * g;
                for (int reg = 0; reg < 4; ++reg)
                    ofp[(size_t)(b * SEQ + grow0 + reg) * 512 + col] = acc[m][n][reg];
            }
        }
    }
}

// ===== NARROW engine (R8/R12-verified): 128x128, BK=64, dbuf ===============
// qk: S[b][2048,2048] fp32 = Q @ K^T (K=512); XCD 1D decode
__global__ __launch_bounds__(256) void gemmn_qk(
    const _Float16* __restrict__ A, const _Float16* __restrict__ B,
    float* __restrict__ of, int bat0) {
    __shared__ char sm[2 * 32768];
    constexpr int T = 8, PA = 512, PB = 512;

    int tid = threadIdx.x, wid = tid >> 6, lane = tid & 63, r = lane & 15, g = lane >> 4;
    int mw = wid >> 1, nw = wid & 1;
    int L = blockIdx.x, xcd = L & 7, s = L >> 3;
    int bz = s >> 5;
    int rem = s & 31;
    int m0 = (xcd * 2 + (rem >> 4)) * 128;
    int n0 = (rem & 15) * 128;

    int b = bat0 + bz;
    const _Float16* Ab = A + ((size_t)(b * SEQ) + m0) * 512;
    const _Float16* Bb = B + ((size_t)(b * SEQ) + n0) * 512;

    const char* gA[4];
    const char* gB[4];
    int ldsw[4];
#pragma unroll
    for (int j = 0; j < 4; ++j) {
        int ci = (j * 4 + wid) * 64 + lane;
        int row = ci >> 3, cl = ci & 7;
        int col16 = cl ^ (row & 7);
        gA[j] = (const char*)Ab + (size_t)row * (PA * 2) + col16 * 16;
        gB[j] = (const char*)Bb + (size_t)row * (PB * 2) + col16 * 16;
        ldsw[j] = (j * 4 + wid) * 1024;
    }
    int offA[4][2], offB[4][2];
#pragma unroll
    for (int m = 0; m < 4; ++m) {
        int rowA = mw * 64 + m * 16 + r;
        int rowB = nw * 64 + m * 16 + r;
#pragma unroll
        for (int ks = 0; ks < 2; ++ks) {
            offA[m][ks] = rowA * 128 + (((ks * 4 + g) ^ (rowA & 7)) * 16);
            offB[m][ks] = rowB * 128 + (((ks * 4 + g) ^ (rowB & 7)) * 16);
        }
    }

    f32x4 acc[4][4];
#pragma unroll
    for (int m = 0; m < 4; ++m)
#pragma unroll
        for (int n = 0; n < 4; ++n) acc[m][n] = (f32x4)(0.0f);

    auto STG = [&](int t, int bb) {
        int ka = t * 128, kb = t * 128;
        char* dA = sm + bb * 32768;
        char* dB = sm + bb * 32768 + 16384;
#pragma unroll
        for (int j = 0; j < 4; ++j) {
            GLOAD_LDS16(gA[j] + ka, dA + ldsw[j]);
            GLOAD_LDS16(gB[j] + kb, dB + ldsw[j]);
        }
    };

    STG(0, 0);
    asm volatile("s_waitcnt vmcnt(0)" ::: "memory");
    __builtin_amdgcn_s_barrier();

#pragma unroll
    for (int t = 0; t < T; ++t) {
        const int buf = t & 1;
        if (t + 1 < T) STG(t + 1, buf ^ 1);
        const char* bA = sm + buf * 32768;
        const char* bB = sm + buf * 32768 + 16384;
        h8 af[4][2], bf[4][2];
#pragma unroll
        for (int m = 0; m < 4; ++m)
#pragma unroll
            for (int ks = 0; ks < 2; ++ks) {
                af[m][ks] = *(const h8*)(bA + offA[m][ks]);
                bf[m][ks] = *(const h8*)(bB + offB[m][ks]);
            }
#pragma unroll
        for (int ks = 0; ks < 2; ++ks)
#pragma unroll
            for (int m = 0; m < 4; ++m)
#pragma unroll
                for (int n = 0; n < 4; ++n)
                    acc[m][n] = MFMA16(af[m][ks], bf[n][ks], acc[m][n]);
        if (t + 1 < T) {
            asm volatile("s_waitcnt vmcnt(0)" ::: "memory");
            __builtin_amdgcn_s_barrier();
        }
    }

    float* sb = of + (size_t)bz * (SEQ * (size_t)SEQ);
#pragma unroll
    for (int n = 0; n < 4; ++n) {
        int col = n0 + nw * 64 + n * 16 + r;
#pragma unroll
        for (int m = 0; m < 4; ++m) {
            int grow0 = m0 + mw * 64 + m * 16 + 4 * g;
            for (int reg = 0; reg < 4; ++reg)
                sb[(size_t)(grow0 + reg) * SEQ + col] = acc[m][n][reg];
        }
    }
}

// ---------------- K3: row softmax, in-place P(f16) over S(f32) --------------
__global__ __launch_bounds__(256) void k3_softmax(float* __restrict__ sbuf) {
    size_t row = blockIdx.x;
    float* srow = sbuf + row * SEQ;
    int tid = threadIdx.x, lane = tid & 63, wid = tid >> 6;
    float4 v0 = *(const float4*)(srow + tid * 8);
    float4 v1 = *(const float4*)(srow + tid * 8 + 4);
    float m = fmaxf(fmaxf(fmaxf(v0.x, v0.y), fmaxf(v0.z, v0.w)),
                    fmaxf(fmaxf(v1.x, v1.y), fmaxf(v1.z, v1.w)));
    for (int d = 1; d < 64; d <<= 1) m = fmaxf(m, __shfl_xor(m, d));
    __shared__ float red1[4], red2[4];
    if (lane == 0) red1[wid] = m;
    __syncthreads();
    m = fmaxf(fmaxf(red1[0], red1[1]), fmaxf(red1[2], red1[3]));
    float e[8];
    e[0] = __expf(v0.x - m); e[1] = __expf(v0.y - m);
    e[2] = __expf(v0.z - m); e[3] = __expf(v0.w - m);
    e[4] = __expf(v1.x - m); e[5] = __expf(v1.y - m);
    e[6] = __expf(v1.z - m); e[7] = __expf(v1.w - m);
    float s = ((e[0] + e[1]) + (e[2] + e[3])) + ((e[4] + e[5]) + (e[6] + e[7]));
    for (int d = 1; d < 64; d <<= 1) s += __shfl_xor(s, d);
    if (lane == 0) red2[wid] = s;
    __syncthreads();
    s = (red2[0] + red2[1]) + (red2[2] + red2[3]);
    float inv = 1.0f / s;
    h8 ph;
    for (int j = 0; j < 8; ++j) ph[j] = (_Float16)(e[j] * inv);
    *(h8*)((char*)srow + (size_t)tid * 16) = ph;   // P row: first 4KB of S row
}

// ---------------- K0a: Wq -> hi|lo stacked (K=1024); Wk,Wv -> hi only -------
__global__ __launch_bounds__(256) void k0a_splitw(
    const float* __restrict__ Wq, const float* __restrict__ Wk, const float* __restrict__ Wv,
    _Float16* __restrict__ wq, _Float16* __restrict__ wkv) {
    int idx = blockIdx.x * 256 + threadIdx.x;   // [0, 3*512*512)
    int p = idx >> 18;
    int rem = idx & 262143;
    int k = rem >> 9, n = rem & 511;
    if (p == 0) {
        float w = Wq[rem];
        _Float16 h = (_Float16)w;
        wq[(size_t)n * 1024 + k] = h;
        wq[(size_t)n * 1024 + 512 + k] = (_Float16)(w - (float)h);
    } else if (p == 1) {
        wkv[(size_t)n * 512 + k] = (_Float16)Wk[rem];
    } else {
        wkv[(size_t)(512 + n) * 512 + k] = (_Float16)Wv[rem];
    }
}

// ---------------- K0b: x -> f16 ---------------------------------------------
__global__ __launch_bounds__(256) void k0b_splitx(
    const float* __restrict__ x, _Float16* __restrict__ xh) {
    size_t i = (size_t)(blockIdx.x * 256 + threadIdx.x) * 4;
    float4 v = *(const float4*)(x + i);
    h4 h;
    h[0] = (_Float16)v.x; h[1] = (_Float16)v.y;
    h[2] = (_Float16)v.z; h[3] = (_Float16)v.w;
    *(h4*)(xh + i) = h;
}

// ---------------------------------------------------------------------------
extern "C" void kernel_launch(void* const* d_in, const int* in_sizes, int n_in,
                              void* d_out, int out_size, void* d_ws, size_t ws_size,
                              hipStream_t stream) {
    const float* x  = (const float*)d_in[0];
    const float* Wq = (const float*)d_in[1];
    const float* bq = (const float*)d_in[2];
    const float* Wk = (const float*)d_in[3];
    const float* bk = (const float*)d_in[4];
    const float* Wv = (const float*)d_in[5];
    const float* bv = (const float*)d_in[6];
    float* out = (float*)d_out;

    char* ws = (char*)d_ws;
    const size_t QSZ = 16777216;   // 16384*512*2B (= one batch of S fp32)
    _Float16* wq  = (_Float16*)(ws);                    // 1MB
    _Float16* wkv = (_Float16*)(ws + 1048576);          // 1MB
    _Float16* xh = (_Float16*)(ws + 3145728);
    _Float16* qh = (_Float16*)(ws + 3145728 + 1 * QSZ);
    _Float16* kh = (_Float16*)(ws + 3145728 + 2 * QSZ);
    _Float16* vt = (_Float16*)(ws + 3145728 + 3 * QSZ);
    const size_t sbase = 3145728 + 4 * QSZ;             // 70,254,592

    const int LDSW = 3 * 49152;   // 144 KB
    hipFuncSetAttribute((const void*)gemmw<0>,
                        hipFuncAttributeMaxDynamicSharedMemorySize, LDSW);
    hipFuncSetAttribute((const void*)gemmw<1>,
                        hipFuncAttributeMaxDynamicSharedMemorySize, LDSW);
    hipFuncSetAttribute((const void*)gemmw<2>,
                        hipFuncAttributeMaxDynamicSharedMemorySize, LDSW);

    k0a_splitw<<<3072, 256, 0, stream>>>(Wq, Wk, Wv, wq, wkv);
    k0b_splitx<<<8192, 256, 0, stream>>>(x, xh);
    gemmw<0><<<256, 512, LDSW, stream>>>(xh, wq, bq, nullptr, qh, nullptr,
                                         nullptr, 0);
    gemmw<1><<<512, 512, LDSW, stream>>>(xh, wkv, bk, bv, kh, vt, nullptr, 0);

    // chunked attention; qk narrow (2 blocks/CU), pv on the WIDE engine
    // (grid nb*32: 8 m-tiles(XCD) x 4 n x nb batches; T=32 rounds).
    size_t avail = (ws_size > sbase) ? (ws_size - sbase) : 0;
    int chunk = (int)(avail / QSZ);
    if (chunk < 1) chunk = 1;
    if (chunk > 8) chunk = 8;
    float* sc = (float*)(ws + sbase);
    for (int b0 = 0; b0 < 8; b0 += chunk) {
        int nb = (8 - b0 < chunk) ? (8 - b0) : chunk;
        gemmn_qk<<<nb * 256, 256, 0, stream>>>(qh, kh, sc, b0);
        k3_softmax<<<dim3(nb * SEQ), 256, 0, stream>>>(sc);
        gemmw<2><<<nb * 32, 512, LDSW, stream>>>((const _Float16*)sc, vt,
                                                 nullptr, nullptr, nullptr,
                                                 nullptr, out, b0);
    }
}

// Round 19
// 169.708 us; speedup vs baseline: 1.1255x; 1.0197x over previous
//
#include <hip/hip_runtime.h>
#include <hip/hip_fp16.h>

#define SEQ 2048
#define DIM 512

typedef __attribute__((ext_vector_type(8))) short short8;
typedef __attribute__((ext_vector_type(4))) float f32x4;
typedef _Float16 h8 __attribute__((ext_vector_type(8)));
typedef _Float16 h4 __attribute__((ext_vector_type(4)));

#define MFMA16(a, b, c) __builtin_amdgcn_mfma_f32_16x16x32_f16((a), (b), (c), 0, 0, 0)

#define GLOAD_LDS16(g, l)                                                              \
    __builtin_amdgcn_global_load_lds(                                                  \
        (const __attribute__((address_space(1))) unsigned int*)(g),                    \
        (__attribute__((address_space(3))) unsigned int*)(l), 16, 0, 0)

// ===== WIDE engine body (R9-verified): 256x128, BK=64, 3 bufs, counted vmcnt
// 512 threads, 144KB LDS, 1 block/CU. L is the mode-local 1D block index.
// MODE 0: projQ  qh[16384,512] = xh @ Wq' (virtual K=1024 = [Wqh|Wql]) + bq
// MODE 1: projKV kh/vt = xh @ wkv (K=512; n0<512 -> K out, else V^T out)
// MODE 2: pv     out[b][2048,512] = P @ V^T (K=2048; P f16 rows pitch 4096)
template <int MODE>
__device__ __forceinline__ void gemmw_body(
    int L, char* sm,
    const _Float16* __restrict__ A, const _Float16* __restrict__ B,
    const float* __restrict__ biasA, const float* __restrict__ biasB,
    _Float16* __restrict__ o0, _Float16* __restrict__ ovt,
    float* __restrict__ ofp, int bat0) {
    constexpr int T  = (MODE == 0) ? 16 : (MODE == 1) ? 8 : 32;
    constexpr int PA = (MODE == 2) ? 4096 : 512;
    constexpr int PB = (MODE == 0) ? 1024 : (MODE == 1) ? 512 : 2048;

    int tid = threadIdx.x, wid = tid >> 6, lane = tid & 63, r = lane & 15, g = lane >> 4;
    int wm = wid >> 1, wn = wid & 1;
    // XCD decode: same-A blocks at consecutive slots on one XCD
    int xcd = L & 7, s = L >> 3;
    int m0, n0, bz = 0;
    if (MODE == 0)      { m0 = (xcd * 8 + (s >> 2)) * 256; n0 = (s & 3) * 128; }
    else if (MODE == 1) { m0 = (xcd * 8 + (s >> 3)) * 256; n0 = (s & 7) * 128; }
    else                { m0 = xcd * 256; bz = s >> 2; n0 = (s & 3) * 128; }

    const _Float16 *Ab, *Bb;
    if (MODE == 2) {
        int b = bat0 + bz;
        Ab = A + (size_t)bz * (SEQ * 4096) + (size_t)m0 * 4096;
        Bb = B + (size_t)b * (512 * SEQ) + (size_t)n0 * 2048;
    } else {
        Ab = A + (size_t)m0 * 512;
        Bb = B + (size_t)n0 * PB;
    }

    const char* gA[4];
    const char* gB[2];
    int ldsA[4], ldsB[2];
#pragma unroll
    for (int j = 0; j < 4; ++j) {
        int ci = j * 512 + tid;
        int row = ci >> 3, cl = ci & 7;
        int col16 = cl ^ (row & 7);
        gA[j] = (const char*)Ab + (size_t)row * (PA * 2) + col16 * 16;
        ldsA[j] = ci * 16;
    }
#pragma unroll
    for (int j = 0; j < 2; ++j) {
        int ci = j * 512 + tid;
        int row = ci >> 3, cl = ci & 7;
        int col16 = cl ^ (row & 7);
        gB[j] = (const char*)Bb + (size_t)row * (PB * 2) + col16 * 16;
        ldsB[j] = ci * 16;
    }
    int offA[4][2], offB[4][2];
#pragma unroll
    for (int m = 0; m < 4; ++m) {
        int rowA = wm * 64 + m * 16 + r;
        int rowB = wn * 64 + m * 16 + r;
#pragma unroll
        for (int ks = 0; ks < 2; ++ks) {
            offA[m][ks] = rowA * 128 + (((ks * 4 + g) ^ (rowA & 7)) * 16);
            offB[m][ks] = rowB * 128 + (((ks * 4 + g) ^ (rowB & 7)) * 16);
        }
    }

    f32x4 acc[4][4];
#pragma unroll
    for (int m = 0; m < 4; ++m)
#pragma unroll
        for (int n = 0; n < 4; ++n) acc[m][n] = (f32x4)(0.0f);

    auto STG = [&](int t, int b) {
        int ka = (MODE == 0) ? ((t & 7) * 128) : (t * 128);
        int kb = t * 128;
        char* dA = sm + b * 49152;
        char* dB = sm + b * 49152 + 32768;
#pragma unroll
        for (int j = 0; j < 4; ++j) GLOAD_LDS16(gA[j] + ka, dA + ldsA[j]);
#pragma unroll
        for (int j = 0; j < 2; ++j) GLOAD_LDS16(gB[j] + kb, dB + ldsB[j]);
    };

    STG(0, 0);
    STG(1, 1);
    asm volatile("s_waitcnt vmcnt(6)" ::: "memory");
    __builtin_amdgcn_s_barrier();

#pragma unroll
    for (int t = 0; t < T; ++t) {
        const int buf = t % 3;
        if (t + 2 < T) STG(t + 2, (t + 2) % 3);
        const char* bA = sm + buf * 49152;
        const char* bB = sm + buf * 49152 + 32768;
        h8 af[4][2], bf[4][2];
#pragma unroll
        for (int m = 0; m < 4; ++m)
#pragma unroll
            for (int ks = 0; ks < 2; ++ks) {
                af[m][ks] = *(const h8*)(bA + offA[m][ks]);
                bf[m][ks] = *(const h8*)(bB + offB[m][ks]);
            }
        __builtin_amdgcn_s_setprio(1);
#pragma unroll
        for (int ks = 0; ks < 2; ++ks)
#pragma unroll
            for (int m = 0; m < 4; ++m)
#pragma unroll
                for (int n = 0; n < 4; ++n)
                    acc[m][n] = MFMA16(af[m][ks], bf[n][ks], acc[m][n]);
        __builtin_amdgcn_s_setprio(0);
        if (t + 2 < T) asm volatile("s_waitcnt vmcnt(6)" ::: "memory");
        else if (t + 1 < T) asm volatile("s_waitcnt vmcnt(0)" ::: "memory");
        if (t + 1 < T) __builtin_amdgcn_s_barrier();
    }

    if (MODE == 0) {
#pragma unroll
        for (int n = 0; n < 4; ++n) {
            int col = n0 + wn * 64 + n * 16 + r;
            float bi = biasA[col];
#pragma unroll
            for (int m = 0; m < 4; ++m) {
                int grow0 = m0 + wm * 64 + m * 16 + 4 * g;
                for (int reg = 0; reg < 4; ++reg)
                    o0[(size_t)(grow0 + reg) * 512 + col] =
                        (_Float16)(acc[m][n][reg] + bi);
            }
        }
    } else if (MODE == 1) {
        int p = n0 >> 9, ncl = n0 & 511;
        if (p == 0) {
#pragma unroll
            for (int n = 0; n < 4; ++n) {
                int col = ncl + wn * 64 + n * 16 + r;
                float bi = biasA[col];
#pragma unroll
                for (int m = 0; m < 4; ++m) {
                    int grow0 = m0 + wm * 64 + m * 16 + 4 * g;
                    for (int reg = 0; reg < 4; ++reg)
                        o0[(size_t)(grow0 + reg) * 512 + col] =
                            (_Float16)(acc[m][n][reg] + bi);
                }
            }
        } else {
            // V^T via LDS transpose -> coalesced 128B-per-thread writes
            __syncthreads();
            _Float16* tt = (_Float16*)sm;    // [128 d][256 s], pitch 264 = 66KB
#pragma unroll
            for (int n = 0; n < 4; ++n) {
                int dloc = wn * 64 + n * 16 + r;
                float bi = biasB[ncl + dloc];
#pragma unroll
                for (int m = 0; m < 4; ++m) {
                    int sloc = wm * 64 + m * 16 + 4 * g;
                    h4 pv;
                    pv[0] = (_Float16)(acc[m][n][0] + bi);
                    pv[1] = (_Float16)(acc[m][n][1] + bi);
                    pv[2] = (_Float16)(acc[m][n][2] + bi);
                    pv[3] = (_Float16)(acc[m][n][3] + bi);
                    *(h4*)(&tt[dloc * 264 + sloc]) = pv;
                }
            }
            __syncthreads();
            int b = m0 >> 11, s0b = m0 & 2047;
            int drow = tid >> 2, part = tid & 3;
            const char* src = (const char*)(tt + drow * 264 + part * 64);
            char* dst = (char*)(ovt + (size_t)b * (512 * 2048) +
                                (size_t)(ncl + drow) * 2048 + s0b + part * 64);
#pragma unroll
            for (int j = 0; j < 8; ++j)
                *(short8*)(dst + j * 16) = *(const short8*)(src + j * 16);
        }
    } else {
        int b = bat0 + bz;
#pragma unroll
        for (int n = 0; n < 4; ++n) {
            int col = n0 + wn * 64 + n * 16 + r;
#pragma unroll
            for (int m = 0; m < 4; ++m) {
                int grow0 = m0 + wm * 64 + m * 16 + 4 * g;
                for (int reg = 0; reg < 4; ++reg)
                    ofp[(size_t)(b * SEQ + grow0 + reg) * 512 + col] = acc[m][n][reg];
            }
        }
    }
}

// ---- fused projections: blocks [0,256) = projQ, [256,768) = projKV --------
__global__ __launch_bounds__(512, 1) void gemmw_proj(
    const _Float16* __restrict__ xh,
    const _Float16* __restrict__ wq, const _Float16* __restrict__ wkv,
    const float* __restrict__ bq, const float* __restrict__ bk,
    const float* __restrict__ bv,
    _Float16* __restrict__ qh, _Float16* __restrict__ kh,
    _Float16* __restrict__ vt) {
    extern __shared__ char sm[];
    int L = blockIdx.x;
    if (L < 256)
        gemmw_body<0>(L, sm, xh, wq, bq, nullptr, qh, nullptr, nullptr, 0);
    else
        gemmw_body<1>(L - 256, sm, xh, wkv, bk, bv, kh, vt, nullptr, 0);
}

// ---- pv on the wide engine -------------------------------------------------
__global__ __launch_bounds__(512, 1) void gemmw_pv(
    const _Float16* __restrict__ pbuf, const _Float16* __restrict__ vt,
    float* __restrict__ out, int bat0) {
    extern __shared__ char sm[];
    gemmw_body<2>(blockIdx.x, sm, pbuf, vt, nullptr, nullptr, nullptr, nullptr,
                  out, bat0);
}

// ===== NARROW engine (R8/R12-verified): 128x128, BK=64, dbuf ===============
// qk: S[b][2048,2048] fp32 = Q @ K^T (K=512); XCD 1D decode
__global__ __launch_bounds__(256) void gemmn_qk(
    const _Float16* __restrict__ A, const _Float16* __restrict__ B,
    float* __restrict__ of, int bat0) {
    __shared__ char sm[2 * 32768];
    constexpr int T = 8, PA = 512, PB = 512;

    int tid = threadIdx.x, wid = tid >> 6, lane = tid & 63, r = lane & 15, g = lane >> 4;
    int mw = wid >> 1, nw = wid & 1;
    int L = blockIdx.x, xcd = L & 7, s = L >> 3;
    int bz = s >> 5;
    int rem = s & 31;
    int m0 = (xcd * 2 + (rem >> 4)) * 128;
    int n0 = (rem & 15) * 128;

    int b = bat0 + bz;
    const _Float16* Ab = A + ((size_t)(b * SEQ) + m0) * 512;
    const _Float16* Bb = B + ((size_t)(b * SEQ) + n0) * 512;

    const char* gA[4];
    const char* gB[4];
    int ldsw[4];
#pragma unroll
    for (int j = 0; j < 4; ++j) {
        int ci = (j * 4 + wid) * 64 + lane;
        int row = ci >> 3, cl = ci & 7;
        int col16 = cl ^ (row & 7);
        gA[j] = (const char*)Ab + (size_t)row * (PA * 2) + col16 * 16;
        gB[j] = (const char*)Bb + (size_t)row * (PB * 2) + col16 * 16;
        ldsw[j] = (j * 4 + wid) * 1024;
    }
    int offA[4][2], offB[4][2];
#pragma unroll
    for (int m = 0; m < 4; ++m) {
        int rowA = mw * 64 + m * 16 + r;
        int rowB = nw * 64 + m * 16 + r;
#pragma unroll
        for (int ks = 0; ks < 2; ++ks) {
            offA[m][ks] = rowA * 128 + (((ks * 4 + g) ^ (rowA & 7)) * 16);
            offB[m][ks] = rowB * 128 + (((ks * 4 + g) ^ (rowB & 7)) * 16);
        }
    }

    f32x4 acc[4][4];
#pragma unroll
    for (int m = 0; m < 4; ++m)
#pragma unroll
        for (int n = 0; n < 4; ++n) acc[m][n] = (f32x4)(0.0f);

    auto STG = [&](int t, int bb) {
        int ka = t * 128, kb = t * 128;
        char* dA = sm + bb * 32768;
        char* dB = sm + bb * 32768 + 16384;
#pragma unroll
        for (int j = 0; j < 4; ++j) {
            GLOAD_LDS16(gA[j] + ka, dA + ldsw[j]);
            GLOAD_LDS16(gB[j] + kb, dB + ldsw[j]);
        }
    };

    STG(0, 0);
    asm volatile("s_waitcnt vmcnt(0)" ::: "memory");
    __builtin_amdgcn_s_barrier();

#pragma unroll
    for (int t = 0; t < T; ++t) {
        const int buf = t & 1;
        if (t + 1 < T) STG(t + 1, buf ^ 1);
        const char* bA = sm + buf * 32768;
        const char* bB = sm + buf * 32768 + 16384;
        h8 af[4][2], bf[4][2];
#pragma unroll
        for (int m = 0; m < 4; ++m)
#pragma unroll
            for (int ks = 0; ks < 2; ++ks) {
                af[m][ks] = *(const h8*)(bA + offA[m][ks]);
                bf[m][ks] = *(const h8*)(bB + offB[m][ks]);
            }
#pragma unroll
        for (int ks = 0; ks < 2; ++ks)
#pragma unroll
            for (int m = 0; m < 4; ++m)
#pragma unroll
                for (int n = 0; n < 4; ++n)
                    acc[m][n] = MFMA16(af[m][ks], bf[n][ks], acc[m][n]);
        if (t + 1 < T) {
            asm volatile("s_waitcnt vmcnt(0)" ::: "memory");
            __builtin_amdgcn_s_barrier();
        }
    }

    float* sb = of + (size_t)bz * (SEQ * (size_t)SEQ);
#pragma unroll
    for (int n = 0; n < 4; ++n) {
        int col = n0 + nw * 64 + n * 16 + r;
#pragma unroll
        for (int m = 0; m < 4; ++m) {
            int grow0 = m0 + mw * 64 + m * 16 + 4 * g;
            for (int reg = 0; reg < 4; ++reg)
                sb[(size_t)(grow0 + reg) * SEQ + col] = acc[m][n][reg];
        }
    }
}

// ---------------- K3: row softmax, in-place P(f16) over S(f32) --------------
__global__ __launch_bounds__(256) void k3_softmax(float* __restrict__ sbuf) {
    size_t row = blockIdx.x;
    float* srow = sbuf + row * SEQ;
    int tid = threadIdx.x, lane = tid & 63, wid = tid >> 6;
    float4 v0 = *(const float4*)(srow + tid * 8);
    float4 v1 = *(const float4*)(srow + tid * 8 + 4);
    float m = fmaxf(fmaxf(fmaxf(v0.x, v0.y), fmaxf(v0.z, v0.w)),
                    fmaxf(fmaxf(v1.x, v1.y), fmaxf(v1.z, v1.w)));
    for (int d = 1; d < 64; d <<= 1) m = fmaxf(m, __shfl_xor(m, d));
    __shared__ float red1[4], red2[4];
    if (lane == 0) red1[wid] = m;
    __syncthreads();
    m = fmaxf(fmaxf(red1[0], red1[1]), fmaxf(red1[2], red1[3]));
    float e[8];
    e[0] = __expf(v0.x - m); e[1] = __expf(v0.y - m);
    e[2] = __expf(v0.z - m); e[3] = __expf(v0.w - m);
    e[4] = __expf(v1.x - m); e[5] = __expf(v1.y - m);
    e[6] = __expf(v1.z - m); e[7] = __expf(v1.w - m);
    float s = ((e[0] + e[1]) + (e[2] + e[3])) + ((e[4] + e[5]) + (e[6] + e[7]));
    for (int d = 1; d < 64; d <<= 1) s += __shfl_xor(s, d);
    if (lane == 0) red2[wid] = s;
    __syncthreads();
    s = (red2[0] + red2[1]) + (red2[2] + red2[3]);
    float inv = 1.0f / s;
    h8 ph;
    for (int j = 0; j < 8; ++j) ph[j] = (_Float16)(e[j] * inv);
    *(h8*)((char*)srow + (size_t)tid * 16) = ph;   // P row: first 4KB of S row
}

// ---------------- K0: fused prep — W split + x -> f16 -----------------------
// blocks [0,3072): W prep (Wq->hi|lo stacked, Wk/Wv->hi); [3072,11264): x cvt
__global__ __launch_bounds__(256) void k0_prep(
    const float* __restrict__ x,
    const float* __restrict__ Wq, const float* __restrict__ Wk,
    const float* __restrict__ Wv,
    _Float16* __restrict__ wq, _Float16* __restrict__ wkv,
    _Float16* __restrict__ xh) {
    int blk = blockIdx.x;
    if (blk < 3072) {
        int idx = blk * 256 + threadIdx.x;   // [0, 3*512*512)
        int p = idx >> 18;
        int rem = idx & 262143;
        int k = rem >> 9, n = rem & 511;
        if (p == 0) {
            float w = Wq[rem];
            _Float16 h = (_Float16)w;
            wq[(size_t)n * 1024 + k] = h;
            wq[(size_t)n * 1024 + 512 + k] = (_Float16)(w - (float)h);
        } else if (p == 1) {
            wkv[(size_t)n * 512 + k] = (_Float16)Wk[rem];
        } else {
            wkv[(size_t)(512 + n) * 512 + k] = (_Float16)Wv[rem];
        }
    } else {
        size_t i = (size_t)((blk - 3072) * 256 + threadIdx.x) * 4;
        float4 v = *(const float4*)(x + i);
        h4 h;
        h[0] = (_Float16)v.x; h[1] = (_Float16)v.y;
        h[2] = (_Float16)v.z; h[3] = (_Float16)v.w;
        *(h4*)(xh + i) = h;
    }
}

// ---------------------------------------------------------------------------
extern "C" void kernel_launch(void* const* d_in, const int* in_sizes, int n_in,
                              void* d_out, int out_size, void* d_ws, size_t ws_size,
                              hipStream_t stream) {
    const float* x  = (const float*)d_in[0];
    const float* Wq = (const float*)d_in[1];
    const float* bq = (const float*)d_in[2];
    const float* Wk = (const float*)d_in[3];
    const float* bk = (const float*)d_in[4];
    const float* Wv = (const float*)d_in[5];
    const float* bv = (const float*)d_in[6];
    float* out = (float*)d_out;

    char* ws = (char*)d_ws;
    const size_t QSZ = 16777216;   // 16384*512*2B (= one batch of S fp32)
    _Float16* wq  = (_Float16*)(ws);                    // 1MB
    _Float16* wkv = (_Float16*)(ws + 1048576);          // 1MB
    _Float16* xh = (_Float16*)(ws + 3145728);
    _Float16* qh = (_Float16*)(ws + 3145728 + 1 * QSZ);
    _Float16* kh = (_Float16*)(ws + 3145728 + 2 * QSZ);
    _Float16* vt = (_Float16*)(ws + 3145728 + 3 * QSZ);
    const size_t sbase = 3145728 + 4 * QSZ;             // 70,254,592

    const int LDSW = 3 * 49152;   // 144 KB
    hipFuncSetAttribute((const void*)gemmw_proj,
                        hipFuncAttributeMaxDynamicSharedMemorySize, LDSW);
    hipFuncSetAttribute((const void*)gemmw_pv,
                        hipFuncAttributeMaxDynamicSharedMemorySize, LDSW);

    k0_prep<<<11264, 256, 0, stream>>>(x, Wq, Wk, Wv, wq, wkv, xh);
    gemmw_proj<<<768, 512, LDSW, stream>>>(xh, wq, wkv, bq, bk, bv, qh, kh, vt);

    size_t avail = (ws_size > sbase) ? (ws_size - sbase) : 0;
    int chunk = (int)(avail / QSZ);
    if (chunk < 1) chunk = 1;
    if (chunk > 8) chunk = 8;
    float* sc = (float*)(ws + sbase);
    for (int b0 = 0; b0 < 8; b0 += chunk) {
        int nb = (8 - b0 < chunk) ? (8 - b0) : chunk;
        gemmn_qk<<<nb * 256, 256, 0, stream>>>(qh, kh, sc, b0);
        k3_softmax<<<dim3(nb * SEQ), 256, 0, stream>>>(sc);
        gemmw_pv<<<nb * 32, 512, LDSW, stream>>>((const _Float16*)sc, vt, out, b0);
    }
}